// Round 14
// baseline (259.966 us; speedup 1.0000x reference)
//
#include <hip/hip_runtime.h>
#include <hip/hip_bf16.h>

#define A_TOK 2048
#define DDIM 1024
#define FDIM 2048
#define NEXP 8
#define NE9 9                      // 8 routed + 1 shared pseudo-expert
#define SLOTS_R (2 * A_TOK)        // 4096 routed slots
#define SLOTS_T (SLOTS_R + A_TOK)  // 6144 incl. shared rows
#define NB1 (2 * FDIM)             // 4096: interleaved [w_in | w_swiglu] rows (32-col blocks)

// k_prep job ranges (512-thread blocks); transpose tiles = 256r x 128c (512B both sides)
#define PREP_TRA_END 1024                     // 16 z * 64 tiles
#define PREP_TRB_END (PREP_TRA_END + 512)     // 8 z * 64 tiles
#define PREP_SH12_END (PREP_TRB_END + 512)    // 4096 row-jobs / 8
#define PREP_SHOUT_END (PREP_SH12_END + 256)  // 1024 rows / 4
#define PREP_NWG (PREP_SHOUT_END + 256)       // + router jobs (2048 tokens / 8)

typedef __attribute__((ext_vector_type(8))) short short8v;   // 8 bf16
typedef __attribute__((ext_vector_type(4))) float f32x4;
typedef __attribute__((ext_vector_type(4))) ushort ushort4v;

#define BARRIER() asm volatile("s_barrier" ::: "memory")
#define VMCNT(n) asm volatile("s_waitcnt vmcnt(" #n ")" ::: "memory")

__device__ __forceinline__ void lds16(const void* g, void* l) {
  __builtin_amdgcn_global_load_lds((const __attribute__((address_space(1))) void*)g,
                                   (__attribute__((address_space(3))) void*)l, 16, 0, 0);
}

__device__ __forceinline__ float sigmoidf_(float x) { return 1.f / (1.f + __expf(-x)); }
__device__ __forceinline__ ushort f2bf(float x) {
  __hip_bfloat16 b = __float2bfloat16(x);
  ushort u; __builtin_memcpy(&u, &b, 2); return u;
}
__device__ __forceinline__ float bf2f(ushort u) {
  union { unsigned int i; float f; } x; x.i = (unsigned int)u << 16; return x.f;
}

// ============== consolidated prep (512 threads/block) ==============
// Transpose scheme: 256r x 128c tiles. LDS = paired cells tileP[ccol][rcell] (uint =
// rows 2*rcell, 2*rcell+1 of column ccol), pitch 129 uints, cell index XOR-swizzled by
// (ccol&7)<<3. Reads from global: 512B/row segments; output rows: 512B segments.
// Staging = scalar uint writes (~2-4-way); gather = 2 scalar uint reads (~2-way) —
// replaces the old 8-way-conflict transpose read (11M conflict cycles measured in R13).
__global__ void k_prep(const float* __restrict__ w_in_e, const float* __restrict__ w_sw_e,
                       const float* __restrict__ w_out_e, const float* __restrict__ w_in_sh,
                       const float* __restrict__ w_sw_sh, const float* __restrict__ w_out_sh,
                       ushort* __restrict__ wt12, ushort* __restrict__ wt_out_t,
                       const float* __restrict__ x, const float* __restrict__ rw,
                       __hip_bfloat16* __restrict__ xbf, int* __restrict__ top_e,
                       float* __restrict__ top_g) {
  __shared__ uint tileP[128 * 129];   // 66 KB
  int b = blockIdx.x, tid = threadIdx.x;
  if (b < PREP_TRB_END) {
    // --- transpose-convert (trA: wt12 remap | trB: wt_out_t plain) ---
    bool isA = (b < PREP_TRA_END);
    const float* in;
    ushort* outbase;
    int r0, c0, inC, outC, which = 0;
    if (isA) {
      int z = b >> 6, p = b & 63;
      int e = z & 7; which = z >> 3;
      in = (which ? w_sw_e : w_in_e) + (size_t)e * DDIM * FDIM;   // [D][F]
      outbase = wt12 + (size_t)e * NB1 * DDIM;
      r0 = (p & 3) * 256; c0 = (p >> 2) * 128;                   // r over D(4), c over F(16)
      inC = FDIM; outC = DDIM;
    } else {
      int b2 = b - PREP_TRA_END;
      int ex = b2 >> 6, p = b2 & 63;
      in = w_out_e + (size_t)ex * FDIM * DDIM;                   // [F][D]
      outbase = wt_out_t + (size_t)ex * DDIM * FDIM;
      r0 = (p & 7) * 256; c0 = (p >> 3) * 128;                   // r over F(8), c over D(8)
      inC = DDIM; outC = FDIM;
    }
    // staging: 8 iters x (32 rows = 16 pairs) x 128 cols
    int rp8 = tid >> 5, c4 = tid & 31;
#pragma unroll
    for (int i = 0; i < 8; i++) {
      int r = i * 32 + rp8 * 2;
      float4 f0 = *(const float4*)(in + (size_t)(r0 + r) * inC + c0 + c4 * 4);
      float4 f1 = *(const float4*)(in + (size_t)(r0 + r + 1) * inC + c0 + c4 * 4);
      int rcell = r >> 1;
      const float* p0f = (const float*)&f0;
      const float* p1f = (const float*)&f1;
#pragma unroll
      for (int j = 0; j < 4; j++) {
        int ccol = c4 * 4 + j;
        uint u = (uint)f2bf(p0f[j]) | ((uint)f2bf(p1f[j]) << 16);
        tileP[ccol * 129 + (rcell ^ ((ccol & 7) << 3))] = u;
      }
    }
    __syncthreads();
    // gather: 16 iters x 8 cols x 64 r-quads
    int oc = tid & 3, rq = (tid >> 2) & 63, half = tid >> 8;
#pragma unroll
    for (int k = 0; k < 16; k++) {
      int c = k * 8 + half * 4 + oc;
      int key = (c & 7) << 3;
      uint u0 = tileP[c * 129 + ((rq * 2) ^ key)];
      uint u1 = tileP[c * 129 + ((rq * 2 + 1) ^ key)];
      ushort4v o = {(ushort)u0, (ushort)(u0 >> 16), (ushort)u1, (ushort)(u1 >> 16)};
      int orow;
      if (isA) {
        int f = c0 + c;
        orow = ((f >> 5) << 6) + (which << 5) + (f & 31);
      } else {
        orow = c0 + c;
      }
      *(ushort4v*)(outbase + (size_t)orow * outC + r0 + rq * 4) = o;
    }
  } else if (b < PREP_SH12_END) {
    // shared in/sw [F][D] -> wt12[8] rows (remap; already K-contiguous)
    int j = b - PREP_TRB_END;
    int rj = j * 8 + (tid >> 6);   // 0..4095
    int l = tid & 63;
    int which = rj & 1, f = rj >> 1;
    const float* src = (which ? w_sw_sh : w_in_sh) + (size_t)f * DDIM;
    int rp = ((f >> 5) << 6) + (which << 5) + (f & 31);
    ushort* dst = wt12 + (size_t)NEXP * NB1 * DDIM + (size_t)rp * DDIM;
#pragma unroll
    for (int i = 0; i < 4; i++) {
      int q = l + 64 * i;
      float4 v = ((const float4*)src)[q];
      ushort4v o = {f2bf(v.x), f2bf(v.y), f2bf(v.z), f2bf(v.w)};
      ((ushort4v*)dst)[q] = o;
    }
  } else if (b < PREP_SHOUT_END) {
    // shared out [D][F] -> wt_out_t[8] rows (plain convert)
    int j = b - PREP_SH12_END;
    int d = j * 4 + (tid >> 7);    // 0..1023
    int l = tid & 127;
    const float* src = w_out_sh + (size_t)d * FDIM;
    ushort* dst = wt_out_t + (size_t)NEXP * DDIM * FDIM + (size_t)d * FDIM;
#pragma unroll
    for (int i = 0; i < 4; i++) {
      int q = l + 128 * i;
      float4 v = ((const float4*)src)[q];
      ushort4v o = {f2bf(v.x), f2bf(v.y), f2bf(v.z), f2bf(v.w)};
      ((ushort4v*)dst)[q] = o;
    }
  } else {
    // router (write-only)
    int j = b - PREP_SHOUT_END;
    int t = j * 8 + (tid >> 6);
    int l = tid & 63;
    const float* xr = x + (size_t)t * DDIM;
    float acc[NEXP];
#pragma unroll
    for (int e = 0; e < NEXP; e++) acc[e] = 0.f;
#pragma unroll
    for (int i = 0; i < 16; i++) {
      int d = i * 64 + l;
      float v = xr[d];
      xbf[(size_t)t * DDIM + d] = __float2bfloat16(v);
      const float* rr = rw + (size_t)d * NEXP;
#pragma unroll
      for (int e = 0; e < NEXP; e++) acc[e] += v * rr[e];
    }
#pragma unroll
    for (int e = 0; e < NEXP; e++) {
#pragma unroll
      for (int s = 32; s > 0; s >>= 1) acc[e] += __shfl_xor(acc[e], s);
    }
    if (l == 0) {
      float b1 = -1e30f, b2 = -1e30f;
      int i1 = 0, i2 = 0;
#pragma unroll
      for (int e = 0; e < NEXP; e++) {
        float v = acc[e];
        if (v > b1) { b2 = b1; i2 = i1; b1 = v; i1 = e; }
        else if (v > b2) { b2 = v; i2 = e; }
      }
      top_e[t * 2 + 0] = i1; top_e[t * 2 + 1] = i2;
      top_g[t * 2 + 0] = sigmoidf_(b1); top_g[t * 2 + 1] = sigmoidf_(b2);
    }
  }
}

// ---------------- scan + dispatch (R9 verbatim) ----------------
__global__ void k_scan(const int* __restrict__ top_e, int* __restrict__ counts,
                       int* __restrict__ offs, int* __restrict__ cursor) {
  __shared__ int hist[NEXP];
  int tid = threadIdx.x;
  if (tid < NEXP) hist[tid] = 0;
  __syncthreads();
  for (int i = tid; i < A_TOK * 2; i += 256) atomicAdd(&hist[top_e[i]], 1);
  __syncthreads();
  if (tid == 0) {
    int s = 0;
    for (int e = 0; e < NEXP; e++) { counts[e] = hist[e]; offs[e] = s; s += hist[e]; cursor[e] = 0; }
    counts[NEXP] = A_TOK;
    offs[NEXP] = s;
  }
}

__global__ void k_dispatch(const float* __restrict__ x, const int* __restrict__ top_e,
                           const float* __restrict__ top_g, const int* __restrict__ offs,
                           int* __restrict__ cursor, int* __restrict__ slot_of,
                           __hip_bfloat16* __restrict__ y) {
  int t = blockIdx.x * 4 + (threadIdx.x >> 6);
  int l = threadIdx.x & 63;
  int e0 = top_e[t * 2 + 0], e1 = top_e[t * 2 + 1];
  float g0 = top_g[t * 2 + 0], g1 = top_g[t * 2 + 1];
  int s0 = 0, s1 = 0;
  if (l == 0) {
    s0 = offs[e0] + atomicAdd(&cursor[e0], 1);
    s1 = offs[e1] + atomicAdd(&cursor[e1], 1);
    slot_of[t * 2 + 0] = s0; slot_of[t * 2 + 1] = s1;
  }
  s0 = __shfl(s0, 0); s1 = __shfl(s1, 0);
  const float* xr = x + (size_t)t * DDIM;
#pragma unroll
  for (int i = 0; i < 16; i++) {
    int d = i * 64 + l;
    float v = xr[d];
    y[(size_t)s0 * DDIM + d] = __float2bfloat16(v * g0);
    y[(size_t)s1 * DDIM + d] = __float2bfloat16(v * g1);
  }
}

// ======== fused in+swiglu grouped GEMM (R9 verbatim, plain 3-D grid) ========
__global__ __launch_bounds__(256, 3) void k_mlp1(
    const ushort* __restrict__ Abase, const ushort* __restrict__ Bbase,
    ushort* __restrict__ Obase, const int* __restrict__ d_cnt,
    const int* __restrict__ d_off) {
  constexpr int K = DDIM, NT = DDIM / 32;
  constexpr int BUF = 16384;
  __shared__ __align__(16) char smem[3 * BUF];
  int e = blockIdx.z;
  int cnt = d_cnt[e];
  int m0 = blockIdx.y * 128;
  if (m0 >= cnt) return;
  int roff = d_off[e];
  int n0 = blockIdx.x * 128;
  const ushort* B = Bbase + (size_t)e * NB1 * DDIM;
  int tid = threadIdx.x, w = tid >> 6, l = tid & 63;
  int wm = w >> 1, wn = w & 1, lr = l & 15, kg = l >> 4;
  size_t arow0 = (size_t)roff + m0;

  int srow = tid >> 2;
  int sgg = (tid & 3) ^ ((tid >> 3) & 3);
  const ushort* pA0 = Abase + (arow0 + srow) * (size_t)K + sgg * 8;
  const ushort* pA1 = pA0 + (size_t)64 * K;
  const ushort* pB0 = B + ((size_t)n0 + srow) * K + sgg * 8;
  const ushort* pB1 = pB0 + (size_t)64 * K;
  int tls = tid * 16;

  int xorg = (kg ^ ((lr >> 1) & 3)) << 4;
  int offA[4], offB[4];
#pragma unroll
  for (int i = 0; i < 4; i++) {
    offA[i] = (wm * 64 + i * 16 + lr) * 64 + xorg;
    offB[i] = 8192 + (wn * 64 + i * 16 + lr) * 64 + xorg;
  }

  f32x4 acc[4][4];
#pragma unroll
  for (int i = 0; i < 4; i++)
#pragma unroll
    for (int j = 0; j < 4; j++) acc[i][j] = {0.f, 0.f, 0.f, 0.f};

#pragma unroll
  for (int pt = 0; pt < 2; ++pt) {
    char* bb = smem + pt * BUF;
    lds16(pA0, bb + tls);         pA0 += 32;
    lds16(pA1, bb + 4096 + tls);  pA1 += 32;
    lds16(pB0, bb + 8192 + tls);  pB0 += 32;
    lds16(pB1, bb + 12288 + tls); pB1 += 32;
  }
  VMCNT(4);
  BARRIER();

  char* b0 = smem;
  char* b1 = smem + BUF;
  char* b2 = smem + 2 * BUF;
  for (int t = 0; t < NT; ++t) {
    bool st = (t + 2) < NT;
    short8v af[4], bf[4];
#pragma unroll
    for (int mf = 0; mf < 4; mf++) af[mf] = *(const short8v*)(b0 + offA[mf]);
#pragma unroll
    for (int nf = 0; nf < 2; nf++) bf[nf] = *(const short8v*)(b0 + offB[nf]);
    if (st) {
      lds16(pA0, b2 + tls);
      lds16(pA1, b2 + 4096 + tls);
    }
    pA0 += 32; pA1 += 32;
    BARRIER();
    __builtin_amdgcn_s_setprio(1);
#pragma unroll
    for (int nf = 0; nf < 2; nf++)
#pragma unroll
      for (int mf = 0; mf < 4; mf++)
        acc[mf][nf] = __builtin_amdgcn_mfma_f32_16x16x32_bf16(af[mf], bf[nf], acc[mf][nf], 0, 0, 0);
    __builtin_amdgcn_s_setprio(0);
    BARRIER();
#pragma unroll
    for (int nf = 2; nf < 4; nf++) bf[nf] = *(const short8v*)(b0 + offB[nf]);
    if (st) {
      lds16(pB0, b2 + 8192 + tls);
      lds16(pB1, b2 + 12288 + tls);
    }
    pB0 += 32; pB1 += 32;
    BARRIER();
    __builtin_amdgcn_s_setprio(1);
#pragma unroll
    for (int nf = 2; nf < 4; nf++)
#pragma unroll
      for (int mf = 0; mf < 4; mf++)
        acc[mf][nf] = __builtin_amdgcn_mfma_f32_16x16x32_bf16(af[mf], bf[nf], acc[mf][nf], 0, 0, 0);
    __builtin_amdgcn_s_setprio(0);
    if (t < NT - 1) {
      if (st) { VMCNT(4); } else { VMCNT(0); }
      BARRIER();
    }
    char* tmp = b0; b0 = b1; b1 = b2; b2 = tmp;
  }

  int j = (n0 >> 6) + wn;
#pragma unroll
  for (int mf = 0; mf < 4; mf++)
#pragma unroll
    for (int nf = 0; nf < 2; nf++)
#pragma unroll
      for (int r = 0; r < 4; r++) {
        int row = m0 + wm * 64 + mf * 16 + kg * 4 + r;
        if (row < cnt) {
          float mid = acc[mf][nf][r];
          float sw = acc[mf][nf + 2][r];
          float hv = mid * sigmoidf_(mid) * sw;
          int col = j * 32 + nf * 16 + lr;
          Obase[((size_t)roff + row) * FDIM + col] = f2bf(hv);
        }
      }
}

// ======== out-proj grouped GEMM, split-K=2, bf16 partials (R5 verbatim) ========
__global__ __launch_bounds__(256, 3) void k_mlp2(
    const ushort* __restrict__ Abase, const ushort* __restrict__ Bbase,
    ushort* __restrict__ part, const int* __restrict__ d_cnt,
    const int* __restrict__ d_off) {
  constexpr int K = FDIM, NT = 1024 / 32;
  constexpr int BUF = 16384;
  __shared__ __align__(16) char smem[3 * BUF];
  int e = blockIdx.z;
  int cnt = d_cnt[e];
  int mt = blockIdx.y >> 1, kz = blockIdx.y & 1;
  int m0 = mt * 128;
  if (m0 >= cnt) return;
  int roff = d_off[e];
  int n0 = blockIdx.x * 128;
  int kbeg = kz * 1024;
  const ushort* B = Bbase + (size_t)e * DDIM * FDIM;
  int tid = threadIdx.x, w = tid >> 6, l = tid & 63;
  int wm = w >> 1, wn = w & 1, lr = l & 15, kg = l >> 4;
  size_t arow0 = (size_t)roff + m0;

  int srow = tid >> 2;
  int sgg = (tid & 3) ^ ((tid >> 3) & 3);
  const ushort* pA0 = Abase + (arow0 + srow) * (size_t)K + kbeg + sgg * 8;
  const ushort* pA1 = pA0 + (size_t)64 * K;
  const ushort* pB0 = B + ((size_t)n0 + srow) * K + kbeg + sgg * 8;
  const ushort* pB1 = pB0 + (size_t)64 * K;
  int tls = tid * 16;

  int xorg = (kg ^ ((lr >> 1) & 3)) << 4;
  int offA[4], offB[4];
#pragma unroll
  for (int i = 0; i < 4; i++) {
    offA[i] = (wm * 64 + i * 16 + lr) * 64 + xorg;
    offB[i] = 8192 + (wn * 64 + i * 16 + lr) * 64 + xorg;
  }

  f32x4 acc[4][4];
#pragma unroll
  for (int i = 0; i < 4; i++)
#pragma unroll
    for (int j = 0; j < 4; j++) acc[i][j] = {0.f, 0.f, 0.f, 0.f};

#pragma unroll
  for (int pt = 0; pt < 2; ++pt) {
    char* bb = smem + pt * BUF;
    lds16(pA0, bb + tls);         pA0 += 32;
    lds16(pA1, bb + 4096 + tls);  pA1 += 32;
    lds16(pB0, bb + 8192 + tls);  pB0 += 32;
    lds16(pB1, bb + 12288 + tls); pB1 += 32;
  }
  VMCNT(4);
  BARRIER();

  char* b0 = smem;
  char* b1 = smem + BUF;
  char* b2 = smem + 2 * BUF;
  for (int t = 0; t < NT; ++t) {
    bool st = (t + 2) < NT;
    short8v af[4], bf[4];
#pragma unroll
    for (int mf = 0; mf < 4; mf++) af[mf] = *(const short8v*)(b0 + offA[mf]);
#pragma unroll
    for (int nf = 0; nf < 2; nf++) bf[nf] = *(const short8v*)(b0 + offB[nf]);
    if (st) {
      lds16(pA0, b2 + tls);
      lds16(pA1, b2 + 4096 + tls);
    }
    pA0 += 32; pA1 += 32;
    BARRIER();
    __builtin_amdgcn_s_setprio(1);
#pragma unroll
    for (int nf = 0; nf < 2; nf++)
#pragma unroll
      for (int mf = 0; mf < 4; mf++)
        acc[mf][nf] = __builtin_amdgcn_mfma_f32_16x16x32_bf16(af[mf], bf[nf], acc[mf][nf], 0, 0, 0);
    __builtin_amdgcn_s_setprio(0);
    BARRIER();
#pragma unroll
    for (int nf = 2; nf < 4; nf++) bf[nf] = *(const short8v*)(b0 + offB[nf]);
    if (st) {
      lds16(pB0, b2 + 8192 + tls);
      lds16(pB1, b2 + 12288 + tls);
    }
    pB0 += 32; pB1 += 32;
    BARRIER();
    __builtin_amdgcn_s_setprio(1);
#pragma unroll
    for (int nf = 2; nf < 4; nf++)
#pragma unroll
      for (int mf = 0; mf < 4; mf++)
        acc[mf][nf] = __builtin_amdgcn_mfma_f32_16x16x32_bf16(af[mf], bf[nf], acc[mf][nf], 0, 0, 0);
    __builtin_amdgcn_s_setprio(0);
    if (t < NT - 1) {
      if (st) { VMCNT(4); } else { VMCNT(0); }
      BARRIER();
    }
    char* tmp = b0; b0 = b1; b1 = b2; b2 = tmp;
  }

  ushort* outp = part + (size_t)kz * SLOTS_T * DDIM;
#pragma unroll
  for (int mf = 0; mf < 4; mf++)
#pragma unroll
    for (int nf = 0; nf < 4; nf++)
#pragma unroll
      for (int r = 0; r < 4; r++) {
        int row = m0 + wm * 64 + mf * 16 + kg * 4 + r;
        if (row < cnt) {
          int col = n0 + wn * 64 + nf * 16 + lr;
          outp[((size_t)roff + row) * DDIM + col] = f2bf(acc[mf][nf][r]);
        }
      }
}

// ------- combine: out[t][d] = sum over {2 kz} x {s0, s1, shared row} of bf16 partials ----
__global__ void k_combine(const ushort* __restrict__ part, const int* __restrict__ slot_of,
                          float* __restrict__ out) {
  int t = blockIdx.x, q = threadIdx.x;
  int rows[3];
  rows[0] = slot_of[t * 2 + 0];
  rows[1] = slot_of[t * 2 + 1];
  rows[2] = SLOTS_R + t;
  size_t P = (size_t)SLOTS_T * DDIM;
  float o[4] = {0.f, 0.f, 0.f, 0.f};
#pragma unroll
  for (int kz = 0; kz < 2; kz++)
#pragma unroll
    for (int i = 0; i < 3; i++) {
      ushort4v v = *(const ushort4v*)(part + kz * P + (size_t)rows[i] * DDIM + q * 4);
#pragma unroll
      for (int j = 0; j < 4; j++) o[j] += bf2f(v[j]);
    }
  float4 ov = {o[0], o[1], o[2], o[3]};
  ((float4*)out)[(size_t)t * (DDIM / 4) + q] = ov;
}

extern "C" void kernel_launch(void* const* d_in, const int* in_sizes, int n_in,
                              void* d_out, int out_size, void* d_ws, size_t ws_size,
                              hipStream_t stream) {
  (void)in_sizes; (void)n_in; (void)out_size; (void)ws_size;
  const float* x        = (const float*)d_in[0];
  const float* router   = (const float*)d_in[1];
  const float* w_in_sh  = (const float*)d_in[2];
  const float* w_out_sh = (const float*)d_in[3];
  const float* w_sw_sh  = (const float*)d_in[4];
  const float* w_in_e   = (const float*)d_in[5];
  const float* w_sw_e   = (const float*)d_in[6];
  const float* w_out_e  = (const float*)d_in[7];
  float* out = (float*)d_out;

  char* ws = (char*)d_ws;
  size_t off = 0;
  auto alloc = [&](size_t bytes) -> char* {
    char* p = ws + off;
    off += (bytes + 255) & ~(size_t)255;
    return p;
  };
  // Ordering: y_all ++ xbf ++ h contiguous (A overreads stay in-bounds; stores count-guarded).
  // part aliases wt12 (dead after k_mlp1; k_mlp2 reads wt_out_t + h only).
  ushort* wt12     = (ushort*)alloc((size_t)NE9 * NB1 * DDIM * 2);   // 75.5 MB
  ushort* wt_out_t = (ushort*)alloc((size_t)NE9 * DDIM * FDIM * 2);  // 37.7 MB
  __hip_bfloat16* y_all = (__hip_bfloat16*)alloc((size_t)SLOTS_R * DDIM * 2);
  __hip_bfloat16* xbf   = (__hip_bfloat16*)alloc((size_t)A_TOK * DDIM * 2);
  ushort* h        = (ushort*)alloc((size_t)SLOTS_T * FDIM * 2);     // 25.2 MB
  int*   counts  = (int*)alloc(64);
  int*   offs    = (int*)alloc(64);
  int*   cursor  = (int*)alloc(64);
  int*   top_e   = (int*)alloc((size_t)A_TOK * 2 * 4);
  float* top_g   = (float*)alloc((size_t)A_TOK * 2 * 4);
  int*   slot_of = (int*)alloc((size_t)A_TOK * 2 * 4);
  (void)alloc(1 << 20);  // guard for mlp2 A-tile overread
  ushort* part = wt12;   // [2][6144][1024] bf16 = 25.2 MB alias

  // 1) prep: trA + trB (256x128 paired-transpose) + shared converts + router
  k_prep<<<dim3(PREP_NWG), 512, 0, stream>>>(
      w_in_e, w_sw_e, w_out_e, w_in_sh, w_sw_sh, w_out_sh,
      wt12, wt_out_t, x, router, xbf, top_e, top_g);

  // 2) scan
  k_scan<<<dim3(1), 256, 0, stream>>>(top_e, counts, offs, cursor);

  // 3) dispatch
  k_dispatch<<<dim3(A_TOK / 4), 256, 0, stream>>>(x, top_e, top_g, offs, cursor, slot_of, y_all);

  // 4) fused in+swiglu (R9 grid)
  k_mlp1<<<dim3(NB1 / 128, A_TOK / 128, NE9), 256, 0, stream>>>(
      (const ushort*)y_all, wt12, h, counts, offs);

  // 5) out-proj, split-K=2 (R5 grid)
  k_mlp2<<<dim3(DDIM / 128, (A_TOK / 128) * 2, NE9), 256, 0, stream>>>(
      h, wt_out_t, part, counts, offs);

  // 6) combine (fully overwrites d_out -> poison-safe)
  k_combine<<<dim3(A_TOK), 256, 0, stream>>>(part, slot_of, out);
}

// Round 15
// 248.637 us; speedup vs baseline: 1.0456x; 1.0456x over previous
//
#include <hip/hip_runtime.h>
#include <hip/hip_bf16.h>

#define A_TOK 2048
#define DDIM 1024
#define FDIM 2048
#define NEXP 8
#define NE9 9                      // 8 routed + 1 shared pseudo-expert
#define SLOTS_R (2 * A_TOK)        // 4096 routed slots
#define SLOTS_T (SLOTS_R + A_TOK)  // 6144 incl. shared rows
#define NB1 (2 * FDIM)             // 4096: interleaved [w_in | w_swiglu] rows (32-col blocks)

// k_prep job ranges: trA tiles 128r x 64c (256B write segments); trB lives in k_mlp1
#define PREP_TRA_END 4096                     // 16 z * 256 tiles (8 r-tiles x 32 c-tiles)
#define PREP_SH12_END (PREP_TRA_END + 1024)   // 4096 row-jobs / 4
#define PREP_SHOUT_END (PREP_SH12_END + 512)  // 1024 rows / 2
#define PREP_NWG (PREP_SHOUT_END + 512)       // + router jobs (2048 tokens / 4)

typedef __attribute__((ext_vector_type(8))) short short8v;   // 8 bf16
typedef __attribute__((ext_vector_type(4))) float f32x4;
typedef __attribute__((ext_vector_type(4))) ushort ushort4v;

#define BARRIER() asm volatile("s_barrier" ::: "memory")
#define VMCNT(n) asm volatile("s_waitcnt vmcnt(" #n ")" ::: "memory")

__device__ __forceinline__ void lds16(const void* g, void* l) {
  __builtin_amdgcn_global_load_lds((const __attribute__((address_space(1))) void*)g,
                                   (__attribute__((address_space(3))) void*)l, 16, 0, 0);
}

__device__ __forceinline__ float sigmoidf_(float x) { return 1.f / (1.f + __expf(-x)); }
__device__ __forceinline__ ushort f2bf(float x) {
  __hip_bfloat16 b = __float2bfloat16(x);
  ushort u; __builtin_memcpy(&u, &b, 2); return u;
}
__device__ __forceinline__ float bf2f(ushort u) {
  union { unsigned int i; float f; } x; x.i = (unsigned int)u << 16; return x.f;
}

// ============== consolidated prep: trA + shared cvt + router (trB lives in k_mlp1) ==============
__global__ void k_prep(const float* __restrict__ w_in_e, const float* __restrict__ w_sw_e,
                       const float* __restrict__ w_in_sh, const float* __restrict__ w_sw_sh,
                       const float* __restrict__ w_out_sh,
                       ushort* __restrict__ wt12, ushort* __restrict__ wt_out_t,
                       const float* __restrict__ x, const float* __restrict__ rw,
                       __hip_bfloat16* __restrict__ xbf, int* __restrict__ top_e,
                       float* __restrict__ top_g) {
  __shared__ ushort tile[128][68];   // 17408 B; row stride 136B (8B-aligned for b64 ops)
  int b = blockIdx.x, tid = threadIdx.x;
  if (b < PREP_TRA_END) {
    // trA: w_in_e/w_sw_e [e][D][F] fp32 -> wt12[e][4096][1024] bf16 (interleaved remap)
    // tile = 128 r (over D) x 64 c (over F): each output rp-row gets 128 elems = 256B.
    int z = b >> 8, p = b & 255;
    int e = z & 7, which = z >> 3;
    const float* in = (which ? w_sw_e : w_in_e) + (size_t)e * DDIM * FDIM;
    ushort* outb = wt12 + (size_t)e * NB1 * DDIM;
    int r0 = (p & 7) * 128, c0 = (p >> 3) * 64;   // r over D (8 tiles), c over F (32 tiles)
    int rr = tid >> 4, cq = tid & 15;
    float4 va[8];
#pragma unroll
    for (int i = 0; i < 8; i++)
      va[i] = *(const float4*)(in + (size_t)(r0 + i * 16 + rr) * FDIM + c0 + cq * 4);
#pragma unroll
    for (int i = 0; i < 8; i++) {
      float4 v = va[i];
      ushort4v o = {f2bf(v.x), f2bf(v.y), f2bf(v.z), f2bf(v.w)};
      *(ushort4v*)&tile[i * 16 + rr][cq * 4] = o;
    }
    __syncthreads();
    int cc = tid >> 5, rq = tid & 31;
#pragma unroll
    for (int i = 0; i < 8; i++) {
      int c = i * 8 + cc;
      int f = c0 + c;
      int rp = ((f >> 5) << 6) + (which << 5) + (f & 31);
      ushort4v o = {tile[rq * 4 + 0][c], tile[rq * 4 + 1][c],
                    tile[rq * 4 + 2][c], tile[rq * 4 + 3][c]};
      *(ushort4v*)(outb + (size_t)rp * DDIM + r0 + rq * 4) = o;
    }
  } else if (b < PREP_SH12_END) {
    // shared in/sw [F][D] -> wt12[8] rows (remap; already K-contiguous)
    int j = b - PREP_TRA_END;
    int rj = j * 4 + (tid >> 6);   // 0..4095
    int l = tid & 63;
    int which = rj & 1, f = rj >> 1;
    const float* src = (which ? w_sw_sh : w_in_sh) + (size_t)f * DDIM;
    int rp = ((f >> 5) << 6) + (which << 5) + (f & 31);
    ushort* dst = wt12 + (size_t)NEXP * NB1 * DDIM + (size_t)rp * DDIM;
#pragma unroll
    for (int i = 0; i < 4; i++) {
      int q = l + 64 * i;
      float4 v = ((const float4*)src)[q];
      ushort4v o = {f2bf(v.x), f2bf(v.y), f2bf(v.z), f2bf(v.w)};
      ((ushort4v*)dst)[q] = o;
    }
  } else if (b < PREP_SHOUT_END) {
    // shared out [D][F] -> wt_out_t[8] rows (plain convert)
    int j = b - PREP_SH12_END;
    int d = j * 2 + (tid >> 7);    // 0..1023
    int l = tid & 127;
    const float* src = w_out_sh + (size_t)d * FDIM;
    ushort* dst = wt_out_t + (size_t)NEXP * DDIM * FDIM + (size_t)d * FDIM;
#pragma unroll
    for (int i = 0; i < 4; i++) {
      int q = l + 128 * i;
      float4 v = ((const float4*)src)[q];
      ushort4v o = {f2bf(v.x), f2bf(v.y), f2bf(v.z), f2bf(v.w)};
      ((ushort4v*)dst)[q] = o;
    }
  } else {
    // router (write-only: no atomics, no pre-zeroed state)
    int j = b - PREP_SHOUT_END;
    int t = j * 4 + (tid >> 6);
    int l = tid & 63;
    const float* xr = x + (size_t)t * DDIM;
    float acc[NEXP];
#pragma unroll
    for (int e = 0; e < NEXP; e++) acc[e] = 0.f;
#pragma unroll
    for (int i = 0; i < 16; i++) {
      int d = i * 64 + l;
      float v = xr[d];
      xbf[(size_t)t * DDIM + d] = __float2bfloat16(v);
      const float* rr = rw + (size_t)d * NEXP;
#pragma unroll
      for (int e = 0; e < NEXP; e++) acc[e] += v * rr[e];
    }
#pragma unroll
    for (int e = 0; e < NEXP; e++) {
#pragma unroll
      for (int s = 32; s > 0; s >>= 1) acc[e] += __shfl_xor(acc[e], s);
    }
    if (l == 0) {
      float b1 = -1e30f, b2 = -1e30f;
      int i1 = 0, i2 = 0;
#pragma unroll
      for (int e = 0; e < NEXP; e++) {
        float v = acc[e];
        if (v > b1) { b2 = b1; i2 = i1; b1 = v; i1 = e; }
        else if (v > b2) { b2 = v; i2 = e; }
      }
      top_e[t * 2 + 0] = i1; top_e[t * 2 + 1] = i2;
      top_g[t * 2 + 0] = sigmoidf_(b1); top_g[t * 2 + 1] = sigmoidf_(b2);
    }
  }
}

// ---------------- scan: histogram of top_e -> counts/offs/cursor (1 block) ----------------
__global__ void k_scan(const int* __restrict__ top_e, int* __restrict__ counts,
                       int* __restrict__ offs, int* __restrict__ cursor) {
  __shared__ int hist[NEXP];
  int tid = threadIdx.x;
  if (tid < NEXP) hist[tid] = 0;
  __syncthreads();
  for (int i = tid; i < A_TOK * 2; i += 256) atomicAdd(&hist[top_e[i]], 1);
  __syncthreads();
  if (tid == 0) {
    int s = 0;
    for (int e = 0; e < NEXP; e++) { counts[e] = hist[e]; offs[e] = s; s += hist[e]; cursor[e] = 0; }
    counts[NEXP] = A_TOK;  // shared pseudo-expert
    offs[NEXP] = s;
  }
}

__global__ void k_dispatch(const float* __restrict__ x, const int* __restrict__ top_e,
                           const float* __restrict__ top_g, const int* __restrict__ offs,
                           int* __restrict__ cursor, int* __restrict__ slot_of,
                           __hip_bfloat16* __restrict__ y) {
  int t = blockIdx.x * 4 + (threadIdx.x >> 6);
  int l = threadIdx.x & 63;
  int e0 = top_e[t * 2 + 0], e1 = top_e[t * 2 + 1];
  float g0 = top_g[t * 2 + 0], g1 = top_g[t * 2 + 1];
  int s0 = 0, s1 = 0;
  if (l == 0) {
    s0 = offs[e0] + atomicAdd(&cursor[e0], 1);
    s1 = offs[e1] + atomicAdd(&cursor[e1], 1);
    slot_of[t * 2 + 0] = s0; slot_of[t * 2 + 1] = s1;
  }
  s0 = __shfl(s0, 0); s1 = __shfl(s1, 0);
  const float* xr = x + (size_t)t * DDIM;
#pragma unroll
  for (int i = 0; i < 16; i++) {
    int d = i * 64 + l;
    float v = xr[d];
    y[(size_t)s0 * DDIM + d] = __float2bfloat16(v * g0);
    y[(size_t)s1 * DDIM + d] = __float2bfloat16(v * g1);
  }
}

// ======== k_mlp1: z<4 = trB transpose jobs (overlap with GEMM); z>=4 = grouped GEMM ========
// GEMM part is R5's verified kernel verbatim (e = z - 4).
__global__ __launch_bounds__(256, 3) void k_mlp1(
    const ushort* __restrict__ Abase, const ushort* __restrict__ Bbase,
    ushort* __restrict__ Obase, const int* __restrict__ d_cnt,
    const int* __restrict__ d_off, const float* __restrict__ w_out_e,
    ushort* __restrict__ wt_out_t) {
  constexpr int K = DDIM, NT = DDIM / 32;
  constexpr int BUF = 16384;
  __shared__ __align__(16) char smem[3 * BUF];
  int z = blockIdx.z;
  int tid = threadIdx.x;
  if (z < 4) {
    // trB: w_out_e [e][F][D] fp32 -> wt_out_t [e][D][F] bf16; 128r(F) x 64c(D) tiles
    ushort (*tile)[68] = (ushort(*)[68])smem;
    int jj = (z * 16 + blockIdx.y) * 32 + blockIdx.x;  // 0..2047
    int ex = jj >> 8, p = jj & 255;                    // 256 tiles/expert
    const float* in = w_out_e + (size_t)ex * FDIM * DDIM;
    ushort* outp = wt_out_t + (size_t)ex * DDIM * FDIM;
    int r0 = (p >> 4) * 128, c0 = (p & 15) * 64;       // r over F (16), c over D (16)
    int rr = tid >> 4, cq = tid & 15;
    float4 va[8];
#pragma unroll
    for (int i = 0; i < 8; i++)
      va[i] = *(const float4*)(in + (size_t)(r0 + i * 16 + rr) * DDIM + c0 + cq * 4);
#pragma unroll
    for (int i = 0; i < 8; i++) {
      float4 v = va[i];
      ushort4v o = {f2bf(v.x), f2bf(v.y), f2bf(v.z), f2bf(v.w)};
      *(ushort4v*)&tile[i * 16 + rr][cq * 4] = o;
    }
    __syncthreads();
    int cc = tid >> 5, rq = tid & 31;
#pragma unroll
    for (int i = 0; i < 8; i++) {
      int c = i * 8 + cc;
      ushort4v o = {tile[rq * 4 + 0][c], tile[rq * 4 + 1][c],
                    tile[rq * 4 + 2][c], tile[rq * 4 + 3][c]};
      *(ushort4v*)(outp + (size_t)(c0 + c) * FDIM + r0 + rq * 4) = o;
    }
    return;
  }
  int e = z - 4;
  int cnt = d_cnt[e];
  int m0 = blockIdx.y * 128;
  if (m0 >= cnt) return;
  int roff = d_off[e];
  int n0 = blockIdx.x * 128;
  const ushort* B = Bbase + (size_t)e * NB1 * DDIM;
  int w = tid >> 6, l = tid & 63;
  int wm = w >> 1, wn = w & 1, lr = l & 15, kg = l >> 4;
  size_t arow0 = (size_t)roff + m0;

  int srow = tid >> 2;
  int sgg = (tid & 3) ^ ((tid >> 3) & 3);
  const ushort* pA0 = Abase + (arow0 + srow) * (size_t)K + sgg * 8;
  const ushort* pA1 = pA0 + (size_t)64 * K;
  const ushort* pB0 = B + ((size_t)n0 + srow) * K + sgg * 8;
  const ushort* pB1 = pB0 + (size_t)64 * K;
  int tls = tid * 16;

  int xorg = (kg ^ ((lr >> 1) & 3)) << 4;
  int offA[4], offB[4];
#pragma unroll
  for (int i = 0; i < 4; i++) {
    offA[i] = (wm * 64 + i * 16 + lr) * 64 + xorg;
    offB[i] = 8192 + (wn * 64 + i * 16 + lr) * 64 + xorg;
  }

  f32x4 acc[4][4];
#pragma unroll
  for (int i = 0; i < 4; i++)
#pragma unroll
    for (int j = 0; j < 4; j++) acc[i][j] = {0.f, 0.f, 0.f, 0.f};

#pragma unroll
  for (int pt = 0; pt < 2; ++pt) {
    char* bb = smem + pt * BUF;
    lds16(pA0, bb + tls);         pA0 += 32;
    lds16(pA1, bb + 4096 + tls);  pA1 += 32;
    lds16(pB0, bb + 8192 + tls);  pB0 += 32;
    lds16(pB1, bb + 12288 + tls); pB1 += 32;
  }
  VMCNT(4);
  BARRIER();

  char* b0 = smem;
  char* b1 = smem + BUF;
  char* b2 = smem + 2 * BUF;
  for (int t = 0; t < NT; ++t) {
    bool st = (t + 2) < NT;
    short8v af[4], bf[4];
#pragma unroll
    for (int mf = 0; mf < 4; mf++) af[mf] = *(const short8v*)(b0 + offA[mf]);
#pragma unroll
    for (int nf = 0; nf < 2; nf++) bf[nf] = *(const short8v*)(b0 + offB[nf]);
    if (st) {
      lds16(pA0, b2 + tls);
      lds16(pA1, b2 + 4096 + tls);
    }
    pA0 += 32; pA1 += 32;
    BARRIER();
    __builtin_amdgcn_s_setprio(1);
#pragma unroll
    for (int nf = 0; nf < 2; nf++)
#pragma unroll
      for (int mf = 0; mf < 4; mf++)
        acc[mf][nf] = __builtin_amdgcn_mfma_f32_16x16x32_bf16(af[mf], bf[nf], acc[mf][nf], 0, 0, 0);
    __builtin_amdgcn_s_setprio(0);
    BARRIER();
#pragma unroll
    for (int nf = 2; nf < 4; nf++) bf[nf] = *(const short8v*)(b0 + offB[nf]);
    if (st) {
      lds16(pB0, b2 + 8192 + tls);
      lds16(pB1, b2 + 12288 + tls);
    }
    pB0 += 32; pB1 += 32;
    BARRIER();
    __builtin_amdgcn_s_setprio(1);
#pragma unroll
    for (int nf = 2; nf < 4; nf++)
#pragma unroll
      for (int mf = 0; mf < 4; mf++)
        acc[mf][nf] = __builtin_amdgcn_mfma_f32_16x16x32_bf16(af[mf], bf[nf], acc[mf][nf], 0, 0, 0);
    __builtin_amdgcn_s_setprio(0);
    if (t < NT - 1) {
      if (st) { VMCNT(4); } else { VMCNT(0); }
      BARRIER();
    }
    char* tmp = b0; b0 = b1; b1 = b2; b2 = tmp;
  }

  int j = (n0 >> 6) + wn;
#pragma unroll
  for (int mf = 0; mf < 4; mf++)
#pragma unroll
    for (int nf = 0; nf < 2; nf++)
#pragma unroll
      for (int r = 0; r < 4; r++) {
        int row = m0 + wm * 64 + mf * 16 + kg * 4 + r;
        if (row < cnt) {
          float mid = acc[mf][nf][r];
          float sw = acc[mf][nf + 2][r];
          float hv = mid * sigmoidf_(mid) * sw;
          int col = j * 32 + nf * 16 + lr;
          Obase[((size_t)roff + row) * FDIM + col] = f2bf(hv);
        }
      }
}

// ======== out-proj grouped GEMM, split-K=2, bf16 partials (R5 verbatim) ========
__global__ __launch_bounds__(256, 3) void k_mlp2(
    const ushort* __restrict__ Abase, const ushort* __restrict__ Bbase,
    ushort* __restrict__ part, const int* __restrict__ d_cnt,
    const int* __restrict__ d_off) {
  constexpr int K = FDIM, NT = 1024 / 32;
  constexpr int BUF = 16384;
  __shared__ __align__(16) char smem[3 * BUF];
  int e = blockIdx.z;
  int cnt = d_cnt[e];
  int mt = blockIdx.y >> 1, kz = blockIdx.y & 1;
  int m0 = mt * 128;
  if (m0 >= cnt) return;
  int roff = d_off[e];
  int n0 = blockIdx.x * 128;
  int kbeg = kz * 1024;
  const ushort* B = Bbase + (size_t)e * DDIM * FDIM;
  int tid = threadIdx.x, w = tid >> 6, l = tid & 63;
  int wm = w >> 1, wn = w & 1, lr = l & 15, kg = l >> 4;
  size_t arow0 = (size_t)roff + m0;

  int srow = tid >> 2;
  int sgg = (tid & 3) ^ ((tid >> 3) & 3);
  const ushort* pA0 = Abase + (arow0 + srow) * (size_t)K + kbeg + sgg * 8;
  const ushort* pA1 = pA0 + (size_t)64 * K;
  const ushort* pB0 = B + ((size_t)n0 + srow) * K + kbeg + sgg * 8;
  const ushort* pB1 = pB0 + (size_t)64 * K;
  int tls = tid * 16;

  int xorg = (kg ^ ((lr >> 1) & 3)) << 4;
  int offA[4], offB[4];
#pragma unroll
  for (int i = 0; i < 4; i++) {
    offA[i] = (wm * 64 + i * 16 + lr) * 64 + xorg;
    offB[i] = 8192 + (wn * 64 + i * 16 + lr) * 64 + xorg;
  }

  f32x4 acc[4][4];
#pragma unroll
  for (int i = 0; i < 4; i++)
#pragma unroll
    for (int j = 0; j < 4; j++) acc[i][j] = {0.f, 0.f, 0.f, 0.f};

#pragma unroll
  for (int pt = 0; pt < 2; ++pt) {
    char* bb = smem + pt * BUF;
    lds16(pA0, bb + tls);         pA0 += 32;
    lds16(pA1, bb + 4096 + tls);  pA1 += 32;
    lds16(pB0, bb + 8192 + tls);  pB0 += 32;
    lds16(pB1, bb + 12288 + tls); pB1 += 32;
  }
  VMCNT(4);
  BARRIER();

  char* b0 = smem;
  char* b1 = smem + BUF;
  char* b2 = smem + 2 * BUF;
  for (int t = 0; t < NT; ++t) {
    bool st = (t + 2) < NT;
    short8v af[4], bf[4];
#pragma unroll
    for (int mf = 0; mf < 4; mf++) af[mf] = *(const short8v*)(b0 + offA[mf]);
#pragma unroll
    for (int nf = 0; nf < 2; nf++) bf[nf] = *(const short8v*)(b0 + offB[nf]);
    if (st) {
      lds16(pA0, b2 + tls);
      lds16(pA1, b2 + 4096 + tls);
    }
    pA0 += 32; pA1 += 32;
    BARRIER();
    __builtin_amdgcn_s_setprio(1);
#pragma unroll
    for (int nf = 0; nf < 2; nf++)
#pragma unroll
      for (int mf = 0; mf < 4; mf++)
        acc[mf][nf] = __builtin_amdgcn_mfma_f32_16x16x32_bf16(af[mf], bf[nf], acc[mf][nf], 0, 0, 0);
    __builtin_amdgcn_s_setprio(0);
    BARRIER();
#pragma unroll
    for (int nf = 2; nf < 4; nf++) bf[nf] = *(const short8v*)(b0 + offB[nf]);
    if (st) {
      lds16(pB0, b2 + 8192 + tls);
      lds16(pB1, b2 + 12288 + tls);
    }
    pB0 += 32; pB1 += 32;
    BARRIER();
    __builtin_amdgcn_s_setprio(1);
#pragma unroll
    for (int nf = 2; nf < 4; nf++)
#pragma unroll
      for (int mf = 0; mf < 4; mf++)
        acc[mf][nf] = __builtin_amdgcn_mfma_f32_16x16x32_bf16(af[mf], bf[nf], acc[mf][nf], 0, 0, 0);
    __builtin_amdgcn_s_setprio(0);
    if (t < NT - 1) {
      if (st) { VMCNT(4); } else { VMCNT(0); }
      BARRIER();
    }
    char* tmp = b0; b0 = b1; b1 = b2; b2 = tmp;
  }

  ushort* outp = part + (size_t)kz * SLOTS_T * DDIM;
#pragma unroll
  for (int mf = 0; mf < 4; mf++)
#pragma unroll
    for (int nf = 0; nf < 4; nf++)
#pragma unroll
      for (int r = 0; r < 4; r++) {
        int row = m0 + wm * 64 + mf * 16 + kg * 4 + r;
        if (row < cnt) {
          int col = n0 + wn * 64 + nf * 16 + lr;
          outp[((size_t)roff + row) * DDIM + col] = f2bf(acc[mf][nf][r]);
        }
      }
}

// ------- combine: out[t][d] = sum over {2 kz} x {s0, s1, shared row} of bf16 partials ----
__global__ void k_combine(const ushort* __restrict__ part, const int* __restrict__ slot_of,
                          float* __restrict__ out) {
  int t = blockIdx.x, q = threadIdx.x;
  int rows[3];
  rows[0] = slot_of[t * 2 + 0];
  rows[1] = slot_of[t * 2 + 1];
  rows[2] = SLOTS_R + t;
  size_t P = (size_t)SLOTS_T * DDIM;
  float o[4] = {0.f, 0.f, 0.f, 0.f};
#pragma unroll
  for (int kz = 0; kz < 2; kz++)
#pragma unroll
    for (int i = 0; i < 3; i++) {
      ushort4v v = *(const ushort4v*)(part + kz * P + (size_t)rows[i] * DDIM + q * 4);
#pragma unroll
      for (int j = 0; j < 4; j++) o[j] += bf2f(v[j]);
    }
  float4 ov = {o[0], o[1], o[2], o[3]};
  ((float4*)out)[(size_t)t * (DDIM / 4) + q] = ov;
}

extern "C" void kernel_launch(void* const* d_in, const int* in_sizes, int n_in,
                              void* d_out, int out_size, void* d_ws, size_t ws_size,
                              hipStream_t stream) {
  (void)in_sizes; (void)n_in; (void)out_size; (void)ws_size;
  const float* x        = (const float*)d_in[0];
  const float* router   = (const float*)d_in[1];
  const float* w_in_sh  = (const float*)d_in[2];
  const float* w_out_sh = (const float*)d_in[3];
  const float* w_sw_sh  = (const float*)d_in[4];
  const float* w_in_e   = (const float*)d_in[5];
  const float* w_sw_e   = (const float*)d_in[6];
  const float* w_out_e  = (const float*)d_in[7];
  float* out = (float*)d_out;

  char* ws = (char*)d_ws;
  size_t off = 0;
  auto alloc = [&](size_t bytes) -> char* {
    char* p = ws + off;
    off += (bytes + 255) & ~(size_t)255;
    return p;
  };
  // Ordering: y_all ++ xbf ++ h contiguous (A overreads stay in-bounds; stores count-guarded).
  // part aliases wt12 (dead after k_mlp1; k_mlp2 reads wt_out_t + h only).
  ushort* wt12     = (ushort*)alloc((size_t)NE9 * NB1 * DDIM * 2);   // 75.5 MB
  ushort* wt_out_t = (ushort*)alloc((size_t)NE9 * DDIM * FDIM * 2);  // 37.7 MB
  __hip_bfloat16* y_all = (__hip_bfloat16*)alloc((size_t)SLOTS_R * DDIM * 2);
  __hip_bfloat16* xbf   = (__hip_bfloat16*)alloc((size_t)A_TOK * DDIM * 2);
  ushort* h        = (ushort*)alloc((size_t)SLOTS_T * FDIM * 2);     // 25.2 MB
  int*   counts  = (int*)alloc(64);
  int*   offs    = (int*)alloc(64);
  int*   cursor  = (int*)alloc(64);
  int*   top_e   = (int*)alloc((size_t)A_TOK * 2 * 4);
  float* top_g   = (float*)alloc((size_t)A_TOK * 2 * 4);
  int*   slot_of = (int*)alloc((size_t)A_TOK * 2 * 4);
  (void)alloc(1 << 20);  // guard for mlp2 A-tile overread
  ushort* part = wt12;   // [2][6144][1024] bf16 = 25.2 MB alias

  // 1) prep: trA + shared converts + router (trB moved into k_mlp1)
  k_prep<<<dim3(PREP_NWG), 256, 0, stream>>>(
      w_in_e, w_sw_e, w_in_sh, w_sw_sh, w_out_sh,
      wt12, wt_out_t, x, router, xbf, top_e, top_g);

  // 2) scan: histogram top_e -> counts/offs/cursor
  k_scan<<<dim3(1), 256, 0, stream>>>(top_e, counts, offs, cursor);

  // 3) dispatch
  k_dispatch<<<dim3(A_TOK / 4), 256, 0, stream>>>(x, top_e, top_g, offs, cursor, slot_of, y_all);

  // 4) fused in+swiglu GEMM (z>=4) + trB transpose jobs (z<4, overlap)
  k_mlp1<<<dim3(NB1 / 128, A_TOK / 128, 4 + NE9), 256, 0, stream>>>(
      (const ushort*)y_all, wt12, h, counts, offs, w_out_e, wt_out_t);

  // 5) out-proj, split-K=2 (reads wt_out_t written in step 4 — stream-ordered)
  k_mlp2<<<dim3(DDIM / 128, (A_TOK / 128) * 2, NE9), 256, 0, stream>>>(
      h, wt_out_t, part, counts, offs);

  // 6) combine (fully overwrites d_out -> poison-safe)
  k_combine<<<dim3(A_TOK), 256, 0, stream>>>(part, slot_of, out);
}